// Round 6
// baseline (539.017 us; speedup 1.0000x reference)
//
#include <hip/hip_runtime.h>
#include <hip/hip_bf16.h>
#include <math.h>

#define D_MODEL 768
#define D_STATE 16
#define D_CONV  4
#define D_INNER 1536
#define DT_RANK 48
#define BATCH   2
#define SEQ     2048
#define BL      (BATCH*SEQ)          // 4096 rows
#define XZ_W    (2*D_INNER)          // 3072
#define SSM_W   (DT_RANK + 2*D_STATE) // 80
#define BC_W    (2*D_STATE)          // 32
#define DTBC_LD (D_INNER + BC_W)     // 1568
#define DTBC_N  1664                 // 13*128 padded GEMM width

#define CH      32                   // time chunks
#define CT      (SEQ/CH)             // 64 steps per chunk
#define NREC    (BATCH*D_INNER*D_STATE) // 49152
#define EG      (D_INNER/128)        // 12

typedef __attribute__((ext_vector_type(8))) short short8;   // 8 bf16
typedef __attribute__((ext_vector_type(4))) float f32x4;

__device__ __forceinline__ float silu_f(float x) { return x / (1.f + __expf(-x)); }
__device__ __forceinline__ float softplus_f(float x) {
    return fmaxf(x, 0.f) + log1pf(__expf(-fabsf(x)));
}

// ======== barrier-free register-streaming bf16 MFMA GEMM ====================
// C = A[M,K] * Bt[N,K]^T. Tile = (MI*32) x 128, 4 waves in 2x2; each wave owns
// (MI*16) x 64 and streams its fragments straight from global each K-step
// (no LDS, no __syncthreads -> compiler emits fine-grained vmcnt, no drains).
// Sibling waves share A (resp. B) rows -> L1 hits. 2-stage register pipeline.
// K must be a multiple of 64. M % (MI*32) == 0, N % 128 == 0 via grid.
// mode 0: C0[row*ldc+col] = v
// mode 1: col<1536 -> C0[row*1536+col] = v (fp32, pre-conv u);
//         col>=1536 -> C1 bf16[row*1536+col-1536] = silu(v)   (silu'd res)
// mode 2: col<1536 -> C0[row*ldc+col] = softplus(v + bias[col]);
//         col<1568 -> plain; col>=1568 (pad) skipped
template<int MI>
__global__ __launch_bounds__(256)
void gemm_stream(const __hip_bfloat16* __restrict__ A,
                 const __hip_bfloat16* __restrict__ Bt,
                 float* __restrict__ C0, void* __restrict__ C1,
                 const float* __restrict__ bias,
                 int K, int ldc, int mode)
{
    const int t = threadIdx.x;
    const int wave = t >> 6, lane = t & 63;
    const int l = lane & 15, kq = lane >> 4;
    const int m0 = blockIdx.y * (MI * 32), n0 = blockIdx.x * 128;
    const int wm = (wave >> 1) * (MI * 16), wn = (wave & 1) * 64;

    const __hip_bfloat16* pa[MI];
    const __hip_bfloat16* pb[4];
    #pragma unroll
    for (int i = 0; i < MI; ++i)
        pa[i] = A + (size_t)(m0 + wm + i * 16 + l) * K + kq * 8;
    #pragma unroll
    for (int j = 0; j < 4; ++j)
        pb[j] = Bt + (size_t)(n0 + wn + j * 16 + l) * K + kq * 8;

    f32x4 acc[MI][4] = {};
    short8 a0[MI], b0[4], a1[MI], b1[4];

#define LD(da, db, off)                                                        \
    _Pragma("unroll") for (int i = 0; i < MI; ++i)                             \
        da[i] = *(const short8*)(pa[i] + (off));                               \
    _Pragma("unroll") for (int j = 0; j < 4; ++j)                              \
        db[j] = *(const short8*)(pb[j] + (off));
#define FM(sa, sb)                                                             \
    _Pragma("unroll") for (int i = 0; i < MI; ++i)                             \
        _Pragma("unroll") for (int j = 0; j < 4; ++j)                          \
            acc[i][j] = __builtin_amdgcn_mfma_f32_16x16x32_bf16(               \
                sa[i], sb[j], acc[i][j], 0, 0, 0);

    LD(a0, b0, 0);
    int k0 = 0;
    for (; k0 + 64 < K; k0 += 64) {
        LD(a1, b1, k0 + 32);
        FM(a0, b0);
        LD(a0, b0, k0 + 64);
        FM(a1, b1);
    }
    LD(a1, b1, K - 32);
    FM(a0, b0);
    FM(a1, b1);
#undef LD
#undef FM

    // C/D layout: col = lane&15, row = (lane>>4)*4 + reg  [m89-verified]
    #pragma unroll
    for (int i = 0; i < MI; ++i)
        #pragma unroll
        for (int j = 0; j < 4; ++j)
            #pragma unroll
            for (int r = 0; r < 4; ++r) {
                int row = m0 + wm + i * 16 + kq * 4 + r;
                int col = n0 + wn + j * 16 + l;
                float v = acc[i][j][r];
                if (mode == 0) {
                    C0[(size_t)row * ldc + col] = v;
                } else if (mode == 1) {
                    if (col < D_INNER)
                        C0[(size_t)row * D_INNER + col] = v;
                    else
                        ((__hip_bfloat16*)C1)[(size_t)row * D_INNER + col - D_INNER] =
                            __float2bfloat16(silu_f(v));
                } else {
                    if (col < D_INNER)
                        C0[(size_t)row * ldc + col] = softplus_f(v + bias[col]);
                    else if (col < DTBC_LD)
                        C0[(size_t)row * ldc + col] = v;
                }
            }
}

// ============ elementwise cast fp32 -> bf16 ============
__global__ __launch_bounds__(256)
void cast_bf16(const float* __restrict__ in, __hip_bfloat16* __restrict__ outp)
{
    int i = blockIdx.x * 256 + threadIdx.x;
    float4 v = ((const float4*)in)[i];
    union { ushort4 u; __hip_bfloat16 h[4]; } p;
    p.h[0] = __float2bfloat16(v.x);
    p.h[1] = __float2bfloat16(v.y);
    p.h[2] = __float2bfloat16(v.z);
    p.h[3] = __float2bfloat16(v.w);
    ((ushort4*)outp)[i] = p.u;
}

// ============ transpose + cast: W[R,C] (row stride lda) fp32 -> Wt[C,R] bf16 =
__global__ __launch_bounds__(256)
void transpose_cast(const float* __restrict__ W, __hip_bfloat16* __restrict__ Wt,
                    int R, int C, int lda)
{
    __shared__ float tile[32][33];
    int c0 = blockIdx.x * 32, r0 = blockIdx.y * 32;
    int tx = threadIdx.x & 31, ty = threadIdx.x >> 5;
    #pragma unroll
    for (int i = 0; i < 32; i += 8)
        tile[ty + i][tx] = W[(size_t)(r0 + ty + i) * lda + c0 + tx];
    __syncthreads();
    #pragma unroll
    for (int i = 0; i < 32; i += 8)
        Wt[(size_t)(c0 + ty + i) * R + r0 + tx] = __float2bfloat16(tile[tx][ty + i]);
}

// ---------------- generic fp32 tiled GEMM (W_eff + fallback path) ----------
__global__ __launch_bounds__(256)
void gemm_f32(const float* __restrict__ A, const float* __restrict__ B,
              float* __restrict__ C, const float* __restrict__ bias,
              int N, int K, int lda, int ldb, int ldc, int epilogue)
{
    __shared__ float As[16][64];
    __shared__ float Bs[16][64];
    const int tid = threadIdx.x;
    const int m0 = blockIdx.y * 64;
    const int n0 = blockIdx.x * 64;
    const int tx = tid & 15, ty = tid >> 4;
    const int a_row = tid >> 2;
    const int a_k4  = (tid & 3) << 2;
    const int b_k   = tid >> 4;
    const int b_n4  = (tid & 15) << 2;
    const bool full_n = (n0 + 64) <= N;

    float acc[4][4] = {};

    for (int k0 = 0; k0 < K; k0 += 16) {
        float4 av = *(const float4*)(A + (size_t)(m0 + a_row) * lda + (k0 + a_k4));
        As[a_k4 + 0][a_row] = av.x;
        As[a_k4 + 1][a_row] = av.y;
        As[a_k4 + 2][a_row] = av.z;
        As[a_k4 + 3][a_row] = av.w;
        if (full_n) {
            *(float4*)&Bs[b_k][b_n4] =
                *(const float4*)(B + (size_t)(k0 + b_k) * ldb + (n0 + b_n4));
        } else {
            #pragma unroll
            for (int j = 0; j < 4; ++j) {
                int col = n0 + b_n4 + j;
                Bs[b_k][b_n4 + j] = (col < N) ? B[(size_t)(k0 + b_k) * ldb + col] : 0.f;
            }
        }
        __syncthreads();
        #pragma unroll
        for (int kk = 0; kk < 16; ++kk) {
            float a[4], bb[4];
            #pragma unroll
            for (int i = 0; i < 4; ++i) a[i]  = As[kk][ty * 4 + i];
            #pragma unroll
            for (int j = 0; j < 4; ++j) bb[j] = Bs[kk][tx * 4 + j];
            #pragma unroll
            for (int i = 0; i < 4; ++i)
                #pragma unroll
                for (int j = 0; j < 4; ++j)
                    acc[i][j] = fmaf(a[i], bb[j], acc[i][j]);
        }
        __syncthreads();
    }

    #pragma unroll
    for (int i = 0; i < 4; ++i) {
        size_t row = (size_t)(m0 + ty * 4 + i);
        #pragma unroll
        for (int j = 0; j < 4; ++j) {
            int col = n0 + tx * 4 + j;
            if (full_n || col < N) {
                float v = acc[i][j];
                if (epilogue == 1) v = softplus_f(v + bias[col]);
                C[row * ldc + col] = v;
            }
        }
    }
}

// ---------------- depthwise causal conv1d(4) + bias + SiLU ----------------
// in: [BL, in_ld]. Writes bf16 ucb (if non-null) and/or fp32 uc32 (if non-null).
__global__ __launch_bounds__(256)
void conv_silu(const float* __restrict__ in, const float* __restrict__ cw,
               const float* __restrict__ cb, float* __restrict__ uc32,
               __hip_bfloat16* __restrict__ ucb, int in_ld)
{
    int idx = blockIdx.x * 256 + threadIdx.x;
    int e  = idx % D_INNER;
    int bt = idx / D_INNER;
    int t  = bt % SEQ;
    const float* base = in + (size_t)bt * in_ld + e;
    float w0 = cw[e * 4 + 0], w1 = cw[e * 4 + 1], w2 = cw[e * 4 + 2], w3 = cw[e * 4 + 3];
    float acc = cb[e] + w3 * base[0];
    if (t >= 1) acc = fmaf(w2, base[-in_ld], acc);
    if (t >= 2) acc = fmaf(w1, base[-2 * in_ld], acc);
    if (t >= 3) acc = fmaf(w0, base[-3 * in_ld], acc);
    float v = silu_f(acc);
    if (uc32) uc32[(size_t)bt * D_INNER + e] = v;
    if (ucb)  ucb[(size_t)bt * D_INNER + e] = __float2bfloat16(v);
}

// ============ chunked parallel SSM scan (thread per channel-half) ============
__device__ __forceinline__ float load_u(const void* uc, int u_bf16, size_t idx)
{
    return u_bf16 ? __bfloat162float(((const __hip_bfloat16*)uc)[idx])
                  : ((const float*)uc)[idx];
}

// Pass 1: local scan h0=0 -> Hend; decay P = exp(Av * sum(dt)).
__global__ __launch_bounds__(256)
void scan_pass1(const float* __restrict__ dt, int dt_ld,
                const void* __restrict__ uc, int u_bf16,
                const float* __restrict__ bc, int bc_ld,
                const float* __restrict__ A_log,
                float* __restrict__ Pbuf, float* __restrict__ Hend)
{
    __shared__ float Bs[CT][16];
    const int tid  = threadIdx.x;
    const int half = tid & 1;
    const int eg   = blockIdx.x % EG;
    const int c    = (blockIdx.x / EG) % CH;
    const int b    = blockIdx.x / (EG * CH);
    const int e    = eg * 128 + (tid >> 1);
    const size_t base = (size_t)b * SEQ + (size_t)c * CT;

    for (int idx = tid; idx < CT * 16; idx += 256) {
        int tr = idx >> 4, col = idx & 15;
        Bs[tr][col] = bc[(base + tr) * bc_ld + col];
    }
    __syncthreads();

    float Av[8];
    {
        float4 a0 = *(const float4*)&A_log[e * D_STATE + half * 8];
        float4 a1 = *(const float4*)&A_log[e * D_STATE + half * 8 + 4];
        Av[0] = -__expf(a0.x); Av[1] = -__expf(a0.y);
        Av[2] = -__expf(a0.z); Av[3] = -__expf(a0.w);
        Av[4] = -__expf(a1.x); Av[5] = -__expf(a1.y);
        Av[6] = -__expf(a1.z); Av[7] = -__expf(a1.w);
    }

    float h[8] = {};
    float sdt = 0.f;

    #pragma unroll 4
    for (int t = 0; t < CT; ++t) {
        size_t r = base + t;
        float dt_v = dt[r * dt_ld + e];
        float u_v  = load_u(uc, u_bf16, r * D_INNER + e);
        sdt += dt_v;
        float du = dt_v * u_v;
        float bl[8];
        *(float4*)&bl[0] = *(const float4*)&Bs[t][half * 8];
        *(float4*)&bl[4] = *(const float4*)&Bs[t][half * 8 + 4];
        #pragma unroll
        for (int n = 0; n < 8; ++n)
            h[n] = fmaf(__expf(dt_v * Av[n]), h[n], du * bl[n]);
    }

    float P[8];
    #pragma unroll
    for (int n = 0; n < 8; ++n) P[n] = __expf(Av[n] * sdt);

    size_t i = (size_t)c * NREC + (size_t)(b * D_INNER + e) * D_STATE + half * 8;
    *(float4*)&Pbuf[i]     = *(float4*)&P[0];
    *(float4*)&Pbuf[i + 4] = *(float4*)&P[4];
    *(float4*)&Hend[i]     = *(float4*)&h[0];
    *(float4*)&Hend[i + 4] = *(float4*)&h[4];
}

// Pass 2: sequential combine over chunks.
__global__ __launch_bounds__(256)
void scan_pass2(float* __restrict__ Pbuf, float* __restrict__ Hend)
{
    size_t i = (size_t)blockIdx.x * 256 + threadIdx.x;
    float H = 0.f;
    for (int c = 0; c < CH; ++c) {
        size_t o = (size_t)c * NREC + i;
        float P  = Pbuf[o];
        float he = Hend[o];
        Pbuf[o] = H;
        H = fmaf(P, H, he);
    }
}

// Pass 3: recompute with true start state; emit y.
// res_presilu: 1 -> res is bf16 silu(res) (multiply directly); 0 -> fp32 raw.
// Fallback may alias dt/yout: both lanes load dt before half==0 stores. Safe.
__global__ __launch_bounds__(256)
void scan_pass3(const float* dt, int dt_ld,
                const void* __restrict__ uc, int u_bf16,
                const float* __restrict__ bc, int bc_ld,
                const void* __restrict__ res, int res_ld, int res_presilu,
                const float* __restrict__ A_log, const float* __restrict__ Dp,
                const float* __restrict__ Hstart, void* yout, int bf16_out)
{
    __shared__ float BCs[CT][32];
    const int tid  = threadIdx.x;
    const int half = tid & 1;
    const int eg   = blockIdx.x % EG;
    const int c    = (blockIdx.x / EG) % CH;
    const int b    = blockIdx.x / (EG * CH);
    const int e    = eg * 128 + (tid >> 1);
    const size_t base = (size_t)b * SEQ + (size_t)c * CT;

    for (int idx = tid; idx < CT * 32; idx += 256) {
        int tr = idx >> 5, col = idx & 31;
        BCs[tr][col] = bc[(base + tr) * bc_ld + col];
    }
    __syncthreads();

    float Av[8];
    {
        float4 a0 = *(const float4*)&A_log[e * D_STATE + half * 8];
        float4 a1 = *(const float4*)&A_log[e * D_STATE + half * 8 + 4];
        Av[0] = -__expf(a0.x); Av[1] = -__expf(a0.y);
        Av[2] = -__expf(a0.z); Av[3] = -__expf(a0.w);
        Av[4] = -__expf(a1.x); Av[5] = -__expf(a1.y);
        Av[6] = -__expf(a1.z); Av[7] = -__expf(a1.w);
    }
    const float Dv = Dp[e];

    float h[8];
    {
        const float* hp = Hstart + (size_t)c * NREC
                        + (size_t)(b * D_INNER + e) * D_STATE + half * 8;
        *(float4*)&h[0] = *(const float4*)hp;
        *(float4*)&h[4] = *(const float4*)(hp + 4);
    }

    #pragma unroll 4
    for (int t = 0; t < CT; ++t) {
        size_t r = base + t;
        float dt_v = dt[r * dt_ld + e];
        float u_v  = load_u(uc, u_bf16, r * D_INNER + e);
        float bl[8], cl[8];
        *(float4*)&bl[0] = *(const float4*)&BCs[t][half * 8];
        *(float4*)&bl[4] = *(const float4*)&BCs[t][half * 8 + 4];
        *(float4*)&cl[0] = *(const float4*)&BCs[t][16 + half * 8];
        *(float4*)&cl[4] = *(const float4*)&BCs[t][16 + half * 8 + 4];
        float du = dt_v * u_v;
        float p = 0.f;
        #pragma unroll
        for (int n = 0; n < 8; ++n) {
            h[n] = fmaf(__expf(dt_v * Av[n]), h[n], du * bl[n]);
            p = fmaf(h[n], cl[n], p);
        }
        p += __shfl_xor(p, 1);
        if (half == 0) {
            float rs = res_presilu
                ? __bfloat162float(((const __hip_bfloat16*)res)[r * res_ld + e])
                : silu_f(((const float*)res)[r * res_ld + e]);
            float y = fmaf(u_v, Dv, p) * rs;
            if (bf16_out) ((__hip_bfloat16*)yout)[r * D_INNER + e] = __float2bfloat16(y);
            else          ((float*)yout)[r * D_INNER + e] = y;
        }
    }
}

extern "C" void kernel_launch(void* const* d_in, const int* in_sizes, int n_in,
                              void* d_out, int out_size, void* d_ws, size_t ws_size,
                              hipStream_t stream)
{
    const float* x      = (const float*)d_in[0];
    const float* W_in   = (const float*)d_in[1];
    const float* conv_w = (const float*)d_in[2];
    const float* conv_b = (const float*)d_in[3];
    const float* W_x    = (const float*)d_in[4];
    const float* W_dt   = (const float*)d_in[5];
    const float* b_dt   = (const float*)d_in[6];
    const float* A_log  = (const float*)d_in[7];
    const float* Dp     = (const float*)d_in[8];
    const float* W_out  = (const float*)d_in[9];
    float* out = (float*)d_out;
    char*  ws  = (char*)d_ws;

    // chunk-state buffers in d_out (dead until final GEMM): 2 x 6,291,456 B
    float* Pbuf = out;
    float* Hend = out + (size_t)CH * NREC;
    const int scan_grid = BATCH * CH * EG;   // 768 blocks

    const bool fast = ws_size >= (size_t)83492864;

    if (fast) {
        // ws layout (bytes), lifetime-aliased:
        //   uraw fp32 @ 0          25,165,824  [GEMM1 -> conv]
        //     yb bf16 @ 0          12,582,912  [pass3 -> GEMM3]   (uraw dead)
        //     Weff    @ 12582912    9,437,184  [post-conv -> WcT] (uraw dead)
        //   srb  bf16 @ 25165824   12,582,912  silu(res) [GEMM1 -> pass3]
        //   ucb  bf16 @ 37748736   12,582,912  [conv -> GEMM2/pass1/pass3]
        //   dtBC fp32 @ 50331648   25,690,112  [GEMM2 -> scans]
        //     xb bf16 @ 50331648    6,291,456  (pre-GEMM2)
        //     wint    @ 56623104    4,718,592  (pre-GEMM2)
        //   WcT  bf16 @ 76021760    5,111,808  [-> GEMM2]
        //   wott bf16 @ 81133568    2,359,296  [-> GEMM3]
        //   total 83,492,864
        float* uraw = (float*)(ws);
        __hip_bfloat16* yb   = (__hip_bfloat16*)(ws);
        float* Weff = (float*)(ws + 12582912);
        __hip_bfloat16* srb  = (__hip_bfloat16*)(ws + 25165824);
        __hip_bfloat16* ucb  = (__hip_bfloat16*)(ws + 37748736);
        float* dtBC = (float*)(ws + 50331648);
        __hip_bfloat16* xb   = (__hip_bfloat16*)(ws + 50331648);
        __hip_bfloat16* wint = (__hip_bfloat16*)(ws + 56623104);
        __hip_bfloat16* WcT  = (__hip_bfloat16*)(ws + 76021760);
        __hip_bfloat16* wott = (__hip_bfloat16*)(ws + 81133568);

        // prep + GEMM1: u|silu(res) = x @ W_in
        cast_bf16<<<(BL * D_MODEL / 4) / 256, 256, 0, stream>>>(x, xb);
        transpose_cast<<<dim3(XZ_W / 32, D_MODEL / 32), 256, 0, stream>>>(
            W_in, wint, D_MODEL, XZ_W, XZ_W);
        gemm_stream<4><<<dim3(XZ_W / 128, BL / 128), 256, 0, stream>>>(
            xb, wint, uraw, (void*)srb, nullptr, D_MODEL, 0, 1);

        // conv + SiLU -> ucb (bf16)
        conv_silu<<<(BL * D_INNER) / 256, 256, 0, stream>>>(
            uraw, conv_w, conv_b, nullptr, ucb, D_INNER);

        // W_eff = W_x[:, :48] @ W_dt ; W_cat^T = [W_eff^T ; W_x[:,48:80]^T]
        gemm_f32<<<dim3(D_INNER / 64, D_INNER / 64), 256, 0, stream>>>(
            W_x, W_dt, Weff, nullptr, D_INNER, DT_RANK, SSM_W, D_INNER, D_INNER, 0);
        transpose_cast<<<dim3(D_INNER / 32, D_INNER / 32), 256, 0, stream>>>(
            Weff, WcT, D_INNER, D_INNER, D_INNER);
        transpose_cast<<<dim3(BC_W / 32, D_INNER / 32), 256, 0, stream>>>(
            W_x + DT_RANK, WcT + (size_t)D_INNER * D_INNER, D_INNER, BC_W, SSM_W);

        // GEMM2: dt|B|C = ucb @ W_cat  [4096,1664->1568] K=1536
        gemm_stream<4><<<dim3(DTBC_N / 128, BL / 128), 256, 0, stream>>>(
            ucb, WcT, dtBC, nullptr, b_dt, D_INNER, DTBC_LD, 2);

        // chunked scan
        scan_pass1<<<scan_grid, 256, 0, stream>>>(
            dtBC, DTBC_LD, (const void*)ucb, 1, dtBC + D_INNER, DTBC_LD,
            A_log, Pbuf, Hend);
        scan_pass2<<<NREC / 256, 256, 0, stream>>>(Pbuf, Hend);
        scan_pass3<<<scan_grid, 256, 0, stream>>>(
            dtBC, DTBC_LD, (const void*)ucb, 1, dtBC + D_INNER, DTBC_LD,
            (const void*)srb, D_INNER, 1, A_log, Dp, Pbuf, (void*)yb, 1);

        // GEMM3: out = y @ W_out  [4096,768] K=1536, 64x128 tile (384 blocks)
        transpose_cast<<<dim3(D_MODEL / 32, D_INNER / 32), 256, 0, stream>>>(
            W_out, wott, D_INNER, D_MODEL, D_MODEL);
        gemm_stream<2><<<dim3(D_MODEL / 128, BL / 64), 256, 0, stream>>>(
            yb, wott, out, nullptr, nullptr, D_INNER, D_MODEL, 0);
    } else {
        // fp32 fallback (round-2 structure)
        float* xz  = (float*)(ws);
        float* uc  = (float*)(ws + 50331648);
        float* smb = (float*)(ws + 75497472);
        float* dtb = (float*)(ws + 76808192);
        float* yf  = dtb;
        gemm_f32<<<dim3(XZ_W / 64, BL / 64), 256, 0, stream>>>(
            x, W_in, xz, nullptr, XZ_W, D_MODEL, D_MODEL, XZ_W, XZ_W, 0);
        conv_silu<<<(BL * D_INNER) / 256, 256, 0, stream>>>(
            xz, conv_w, conv_b, uc, nullptr, XZ_W);
        gemm_f32<<<dim3(2, BL / 64), 256, 0, stream>>>(
            uc, W_x, smb, nullptr, SSM_W, D_INNER, D_INNER, SSM_W, SSM_W, 0);
        gemm_f32<<<dim3(D_INNER / 64, BL / 64), 256, 0, stream>>>(
            smb, W_dt, dtb, b_dt, D_INNER, DT_RANK, SSM_W, D_INNER, D_INNER, 1);
        scan_pass1<<<scan_grid, 256, 0, stream>>>(
            dtb, D_INNER, (const void*)uc, 0, smb + DT_RANK, SSM_W,
            A_log, Pbuf, Hend);
        scan_pass2<<<NREC / 256, 256, 0, stream>>>(Pbuf, Hend);
        scan_pass3<<<scan_grid, 256, 0, stream>>>(
            dtb, D_INNER, (const void*)uc, 0, smb + DT_RANK, SSM_W,
            (const void*)(xz + D_INNER), XZ_W, 0, A_log, Dp, Pbuf, (void*)yf, 0);
        gemm_f32<<<dim3(D_MODEL / 64, BL / 64), 256, 0, stream>>>(
            yf, W_out, out, nullptr, D_MODEL, D_INNER, D_INNER, D_MODEL, D_MODEL, 0);
    }
}